// Round 1
// baseline (1318.505 us; speedup 1.0000x reference)
//
#include <hip/hip_runtime.h>
#include <math.h>

#define D_MODEL 1024
#define HIDDEN  4096
#define NEXP    8
#define NSHARED 2
#define NVEXP   10   // 8 routed + 2 shared

typedef __attribute__((ext_vector_type(8))) short short8;
typedef __attribute__((ext_vector_type(4))) float floatx4;

__device__ __forceinline__ unsigned short f2bf(float f) {
    unsigned int u = __float_as_uint(f);
    unsigned int r = (u + 0x7fffu + ((u >> 16) & 1u)) >> 16;
    return (unsigned short)r;
}

__device__ __forceinline__ void gll16(const void* g, void* l) {
    __builtin_amdgcn_global_load_lds(
        (const __attribute__((address_space(1))) unsigned int*)g,
        (__attribute__((address_space(3))) unsigned int*)l, 16, 0, 0);
}

// ---------------- cast x (fp32 -> bf16), 8 elems/thread ----------------
__global__ __launch_bounds__(256) void cast_x_kernel(const float* __restrict__ x,
                                                     unsigned short* __restrict__ xb) {
    int i = blockIdx.x * 256 + threadIdx.x;
    const float4* x4 = (const float4*)x;
    float4 a = x4[i * 2], b = x4[i * 2 + 1];
    uint4 o;
    o.x = f2bf(a.x) | ((unsigned)f2bf(a.y) << 16);
    o.y = f2bf(a.z) | ((unsigned)f2bf(a.w) << 16);
    o.z = f2bf(b.x) | ((unsigned)f2bf(b.y) << 16);
    o.w = f2bf(b.z) | ((unsigned)f2bf(b.w) << 16);
    ((uint4*)xb)[i] = o;
}

// ------- transpose + cast: src fp32 [R][C]  ->  dst bf16 [C][R] --------
__global__ __launch_bounds__(256) void transpose_cast_kernel(
        const float* __restrict__ srcA, const float* __restrict__ srcB, int splitZ,
        int R, int C, unsigned short* __restrict__ dst) {
    int z = blockIdx.z;
    const float* src = (z < splitZ) ? srcA + (size_t)z * R * C
                                    : srcB + (size_t)(z - splitZ) * R * C;
    unsigned short* d = dst + (size_t)z * (size_t)R * C;
    int c0 = blockIdx.x * 64, r0 = blockIdx.y * 64;
    __shared__ float tile[64][65];
    int t = threadIdx.x;
    int rl = t >> 4, cl = (t & 15) * 4;
#pragma unroll
    for (int p = 0; p < 4; ++p) {
        int r = p * 16 + rl;
        const float4 v = *(const float4*)&src[(size_t)(r0 + r) * C + c0 + cl];
        tile[r][cl] = v.x; tile[r][cl + 1] = v.y; tile[r][cl + 2] = v.z; tile[r][cl + 3] = v.w;
    }
    __syncthreads();
    int oc = t >> 2, seg = t & 3;
    unsigned int u[8];
#pragma unroll
    for (int i = 0; i < 8; ++i) {
        unsigned short lo = f2bf(tile[seg * 16 + 2 * i][oc]);
        unsigned short hi = f2bf(tile[seg * 16 + 2 * i + 1][oc]);
        u[i] = lo | ((unsigned)hi << 16);
    }
    uint4* dp = (uint4*)&d[(size_t)(c0 + oc) * R + r0 + seg * 16];
    dp[0] = make_uint4(u[0], u[1], u[2], u[3]);
    dp[1] = make_uint4(u[4], u[5], u[6], u[7]);
}

// ---------------- router: wave per token, fp32 gates -------------------
__global__ __launch_bounds__(256) void router_kernel(
        const float* __restrict__ x, const float* __restrict__ rW,
        const float* __restrict__ rb, int* __restrict__ te, float* __restrict__ tw,
        int* __restrict__ cnt) {
    __shared__ float rws[8 * 1024];   // rws[e][d]
    int tid = threadIdx.x;
    for (int i = tid; i < 8192; i += 256) {
        int dd = i >> 3, e = i & 7;
        rws[e * 1024 + dd] = rW[i];
    }
    __syncthreads();
    int tok = blockIdx.x * 4 + (tid >> 6);
    int lane = tid & 63;
    const float* xr = x + (size_t)tok * D_MODEL;
    float acc[8];
#pragma unroll
    for (int e = 0; e < 8; ++e) acc[e] = 0.f;
    for (int k = 0; k < 16; ++k) {
        int dd = k * 64 + lane;
        float xv = xr[dd];
#pragma unroll
        for (int e = 0; e < 8; ++e) acc[e] += xv * rws[e * 1024 + dd];
    }
#pragma unroll
    for (int m = 1; m < 64; m <<= 1) {
#pragma unroll
        for (int e = 0; e < 8; ++e) acc[e] += __shfl_xor(acc[e], m);
    }
    if (lane == 0) {
        float g[8];
#pragma unroll
        for (int e = 0; e < 8; ++e) g[e] = acc[e] + rb[e];
        int i0 = 0; float v0 = g[0];
#pragma unroll
        for (int e = 1; e < 8; ++e) if (g[e] > v0) { v0 = g[e]; i0 = e; }
        int i1 = -1; float v1 = -1e30f;
#pragma unroll
        for (int e = 0; e < 8; ++e) if (e != i0 && g[e] > v1) { v1 = g[e]; i1 = e; }
        float ex = expf(v1 - v0);
        float p0 = 1.0f / (1.0f + ex);
        float p1 = 1.0f - p0;
        te[tok * 2] = i0; te[tok * 2 + 1] = i1;
        tw[tok * 2] = p0; tw[tok * 2 + 1] = p1;
        atomicAdd(cnt + i0, 1);
        atomicAdd(cnt + i1, 1);
    }
}

__global__ void scan_kernel(const int* __restrict__ cnt, int* __restrict__ offs,
                            int* __restrict__ cnt2) {
    if (threadIdx.x == 0) {
        int o = 0;
        for (int e = 0; e < 8; ++e) { offs[e] = o; o += cnt[e]; }
    }
    if (threadIdx.x < 8) cnt2[threadIdx.x] = 0;
}

__global__ __launch_bounds__(256) void scatter_kernel(
        const int* __restrict__ te, const float* __restrict__ tw,
        const int* __restrict__ offs, int* __restrict__ cnt2,
        int* __restrict__ ptok, float* __restrict__ pw, int T) {
    int t = blockIdx.x * 256 + threadIdx.x;
    int e0 = te[2 * t], e1 = te[2 * t + 1];
    int s0 = atomicAdd(cnt2 + e0, 1);
    int pos0 = offs[e0] + s0;
    ptok[pos0] = t; pw[pos0] = tw[2 * t];
    int s1 = atomicAdd(cnt2 + e1, 1);
    int pos1 = offs[e1] + s1;
    ptok[pos1] = t; pw[pos1] = tw[2 * t + 1];
    // shared experts: all tokens, weight 0.5
    ptok[2 * T + t] = t;      pw[2 * T + t] = 0.5f;
    ptok[3 * T + t] = t;      pw[3 * T + t] = 0.5f;
}

// ---------------- grouped MFMA GEMM (m97-style) ------------------------
// PHASE 1: C = gelu(gather(xb) @ W1T^T + b1) -> h (bf16)
// PHASE 2: out[token] += w_p * (h @ W2T^T + b2)   (atomic)
// Tile: BM=128, BN=128, BK=64. 4 waves (2x2), wave tile 64x64, 16x16x32 MFMA.
// LDS layout in fragment order: [frag(8)][kstep(2)][lane(64)][8 bf16] per operand.
template <int KDIM, int PHASE>
__global__ __launch_bounds__(256) void moe_gemm(
        const unsigned short* __restrict__ Wt,    // [10][NDIM][KDIM] bf16 (B^T)
        const unsigned short* __restrict__ Abase, // ph1: xb [T][1024]; ph2: h [16384][4096]
        const float* __restrict__ bias,           // ph1: b1 [8][H]; ph2: b2 [8][D]
        const float* __restrict__ sbias,          // ph1: sb1; ph2: sb2
        const int* __restrict__ counts, const int* __restrict__ offs,
        const int* __restrict__ ptok, const float* __restrict__ pw,
        unsigned short* __restrict__ hout,        // ph1 output
        float* __restrict__ out) {                // ph2 output
    const int z = blockIdx.z;
    int cnt, base;
    if (z < NEXP) { cnt = counts[z]; base = offs[z]; }
    else          { cnt = 4096;      base = 8192 + (z - NEXP) * 4096; }
    const int mtile = blockIdx.y;
    if (mtile * 128 >= cnt) return;
    const int ntile = blockIdx.x;
    const int tid = threadIdx.x;
    const int wave = tid >> 6, lane = tid & 63;
    const int wm = wave >> 1, wn = wave & 1;

    __shared__ __align__(16) short As[8 * 2 * 512];
    __shared__ __align__(16) short Bs[8 * 2 * 512];

    const int NDIM = (PHASE == 1) ? HIDDEN : D_MODEL;
    const unsigned short* We = Wt + (size_t)z * NDIM * KDIM;
    const float* be = (z < NEXP) ? bias + (size_t)z * NDIM
                                 : sbias + (size_t)(z - NEXP) * NDIM;

    const int koff = (wave & 1) * 32 + (lane >> 4) * 8;
    const unsigned short* aptr[4];
    const unsigned short* bptr[4];
    short* ldsA[4];
    short* ldsB[4];
#pragma unroll
    for (int j = 0; j < 4; ++j) {
        int mf = 2 * j + wm;
        int r = mf * 16 + (lane & 15);
        int idx = mtile * 128 + r;
        if (idx >= cnt) idx = cnt - 1;
        if (PHASE == 1) {
            int tok = ptok[base + idx];
            aptr[j] = Abase + (size_t)tok * KDIM + koff;
        } else {
            aptr[j] = Abase + (size_t)(base + idx) * KDIM + koff;
        }
        int nrow = ntile * 128 + r;
        bptr[j] = We + (size_t)nrow * KDIM + koff;
        int fr = mf * 2 + (wave & 1);
        ldsA[j] = As + fr * 512;
        ldsB[j] = Bs + fr * 512;
    }

    floatx4 acc[4][4];
#pragma unroll
    for (int s = 0; s < 4; ++s)
#pragma unroll
        for (int n = 0; n < 4; ++n) acc[s][n] = (floatx4){0.f, 0.f, 0.f, 0.f};

    const int NK = KDIM / 64;
    for (int kc = 0; kc < NK; ++kc) {
        __syncthreads();
#pragma unroll
        for (int j = 0; j < 4; ++j) {
            gll16(aptr[j], ldsA[j]);
            gll16(bptr[j], ldsB[j]);
            aptr[j] += 64;
            bptr[j] += 64;
        }
        __syncthreads();
#pragma unroll
        for (int ks = 0; ks < 2; ++ks) {
            short8 af[4], bfr[4];
#pragma unroll
            for (int s = 0; s < 4; ++s)
                af[s] = *(const short8*)(As + ((wm * 4 + s) * 2 + ks) * 512 + lane * 8);
#pragma unroll
            for (int n = 0; n < 4; ++n)
                bfr[n] = *(const short8*)(Bs + ((wn * 4 + n) * 2 + ks) * 512 + lane * 8);
#pragma unroll
            for (int s = 0; s < 4; ++s)
#pragma unroll
                for (int n = 0; n < 4; ++n)
                    acc[s][n] = __builtin_amdgcn_mfma_f32_16x16x32_bf16(af[s], bfr[n], acc[s][n], 0, 0, 0);
        }
    }

    const int gcb = ntile * 128 + wn * 64;
    const int rbq = mtile * 128 + wm * 64 + ((lane >> 4) * 4);

    if (PHASE == 1) {
#pragma unroll
        for (int n = 0; n < 4; ++n) {
            int c = gcb + n * 16 + (lane & 15);
            float bv = be[c];
#pragma unroll
            for (int s = 0; s < 4; ++s) {
#pragma unroll
                for (int reg = 0; reg < 4; ++reg) {
                    int r = rbq + s * 16 + reg;
                    if (r < cnt) {
                        float v = acc[s][n][reg] + bv;
                        float g = 0.5f * v * (1.0f + erff(v * 0.70710678118654752f));
                        hout[(size_t)(base + r) * HIDDEN + c] = f2bf(g);
                    }
                }
            }
        }
    } else {
        float bv[4];
        int cc[4];
#pragma unroll
        for (int n = 0; n < 4; ++n) {
            cc[n] = gcb + n * 16 + (lane & 15);
            bv[n] = be[cc[n]];
        }
#pragma unroll
        for (int s = 0; s < 4; ++s) {
#pragma unroll
            for (int reg = 0; reg < 4; ++reg) {
                int r = rbq + s * 16 + reg;
                if (r < cnt) {
                    int p = base + r;
                    int tok = ptok[p];
                    float w = pw[p];
                    float* orow = out + (size_t)tok * D_MODEL;
#pragma unroll
                    for (int n = 0; n < 4; ++n)
                        atomicAdd(orow + cc[n], (acc[s][n][reg] + bv[n]) * w);
                }
            }
        }
    }
}

extern "C" void kernel_launch(void* const* d_in, const int* in_sizes, int n_in,
                              void* d_out, int out_size, void* d_ws, size_t ws_size,
                              hipStream_t stream) {
    const float* x   = (const float*)d_in[0];
    const float* rW  = (const float*)d_in[1];
    const float* rb  = (const float*)d_in[2];
    const float* W1  = (const float*)d_in[3];
    const float* b1  = (const float*)d_in[4];
    const float* W2  = (const float*)d_in[5];
    const float* b2  = (const float*)d_in[6];
    const float* sW1 = (const float*)d_in[7];
    const float* sb1 = (const float*)d_in[8];
    const float* sW2 = (const float*)d_in[9];
    const float* sb2 = (const float*)d_in[10];
    float* out = (float*)d_out;

    const int T = in_sizes[0] / D_MODEL;     // 4096
    const int NPAIR = 4 * T;                 // 16384 (2 routed + 2 shared per token)

    char* ws = (char*)d_ws;
    size_t o = 0;
    auto alloc = [&](size_t bytes) -> void* {
        void* p = ws + o;
        o += (bytes + 255) & ~(size_t)255;
        return p;
    };
    unsigned short* xb   = (unsigned short*)alloc((size_t)T * D_MODEL * 2);
    unsigned short* W1T  = (unsigned short*)alloc((size_t)NVEXP * HIDDEN * D_MODEL * 2);
    unsigned short* W2T  = (unsigned short*)alloc((size_t)NVEXP * D_MODEL * HIDDEN * 2);
    unsigned short* hbuf = (unsigned short*)alloc((size_t)NPAIR * HIDDEN * 2);
    int*   ptok = (int*)alloc((size_t)NPAIR * 4);
    float* pwb  = (float*)alloc((size_t)NPAIR * 4);
    int*   te   = (int*)alloc((size_t)T * 2 * 4);
    float* tw   = (float*)alloc((size_t)T * 2 * 4);
    int*   cnt  = (int*)alloc(64);
    int*   offs = (int*)alloc(64);
    int*   cnt2 = (int*)alloc(64);
    (void)ws_size; (void)n_in;

    hipMemsetAsync(out, 0, (size_t)out_size * 4, stream);
    hipMemsetAsync(cnt, 0, 64, stream);

    cast_x_kernel<<<(T * D_MODEL) / (8 * 256), 256, 0, stream>>>(x, xb);
    // W1 group: [1024][4096] -> [4096][1024]
    transpose_cast_kernel<<<dim3(HIDDEN / 64, D_MODEL / 64, NVEXP), 256, 0, stream>>>(
        W1, sW1, NEXP, D_MODEL, HIDDEN, W1T);
    // W2 group: [4096][1024] -> [1024][4096]
    transpose_cast_kernel<<<dim3(D_MODEL / 64, HIDDEN / 64, NVEXP), 256, 0, stream>>>(
        W2, sW2, NEXP, HIDDEN, D_MODEL, W2T);

    router_kernel<<<T / 4, 256, 0, stream>>>(x, rW, rb, te, tw, cnt);
    scan_kernel<<<1, 64, 0, stream>>>(cnt, offs, cnt2);
    scatter_kernel<<<T / 256, 256, 0, stream>>>(te, tw, offs, cnt2, ptok, pwb, T);

    moe_gemm<D_MODEL, 1><<<dim3(HIDDEN / 128, 32, NVEXP), 256, 0, stream>>>(
        W1T, xb, b1, sb1, cnt, offs, ptok, pwb, hbuf, nullptr);
    moe_gemm<HIDDEN, 2><<<dim3(D_MODEL / 128, 32, NVEXP), 256, 0, stream>>>(
        W2T, hbuf, b2, sb2, cnt, offs, ptok, pwb, nullptr, out);
}

// Round 2
// 1055.381 us; speedup vs baseline: 1.2493x; 1.2493x over previous
//
#include <hip/hip_runtime.h>
#include <math.h>

#define D_MODEL 1024
#define HIDDEN  4096
#define NEXP    8
#define NVEXP   10   // 8 routed + 2 shared

typedef __attribute__((ext_vector_type(8))) short short8;
typedef __attribute__((ext_vector_type(4))) float floatx4;

__device__ __forceinline__ unsigned short f2bf(float f) {
    unsigned int u = __float_as_uint(f);
    unsigned int r = (u + 0x7fffu + ((u >> 16) & 1u)) >> 16;
    return (unsigned short)r;
}

__device__ __forceinline__ void gll16(const void* g, void* l) {
    __builtin_amdgcn_global_load_lds(
        (const __attribute__((address_space(1))) unsigned int*)g,
        (__attribute__((address_space(3))) unsigned int*)l, 16, 0, 0);
}

// ---------------- router: wave per token, fp32 gates -------------------
__global__ __launch_bounds__(256) void router_kernel(
        const float* __restrict__ x, const float* __restrict__ rW,
        const float* __restrict__ rb, int* __restrict__ te, float* __restrict__ tw,
        int* __restrict__ cnt) {
    __shared__ float rws[8 * 1024];   // rws[e][d]
    int tid = threadIdx.x;
    for (int i = tid; i < 8192; i += 256) {
        int dd = i >> 3, e = i & 7;
        rws[e * 1024 + dd] = rW[i];
    }
    __syncthreads();
    int tok = blockIdx.x * 4 + (tid >> 6);
    int lane = tid & 63;
    const float* xr = x + (size_t)tok * D_MODEL;
    float acc[8];
#pragma unroll
    for (int e = 0; e < 8; ++e) acc[e] = 0.f;
    for (int k = 0; k < 16; ++k) {
        int dd = k * 64 + lane;
        float xv = xr[dd];
#pragma unroll
        for (int e = 0; e < 8; ++e) acc[e] += xv * rws[e * 1024 + dd];
    }
#pragma unroll
    for (int m = 1; m < 64; m <<= 1) {
#pragma unroll
        for (int e = 0; e < 8; ++e) acc[e] += __shfl_xor(acc[e], m);
    }
    if (lane == 0) {
        float g[8];
#pragma unroll
        for (int e = 0; e < 8; ++e) g[e] = acc[e] + rb[e];
        int i0 = 0; float v0 = g[0];
#pragma unroll
        for (int e = 1; e < 8; ++e) if (g[e] > v0) { v0 = g[e]; i0 = e; }
        int i1 = -1; float v1 = -1e30f;
#pragma unroll
        for (int e = 0; e < 8; ++e) if (e != i0 && g[e] > v1) { v1 = g[e]; i1 = e; }
        float ex = expf(v1 - v0);
        float p0 = 1.0f / (1.0f + ex);
        float p1 = 1.0f - p0;
        te[tok * 2] = i0; te[tok * 2 + 1] = i1;
        tw[tok * 2] = p0; tw[tok * 2 + 1] = p1;
        atomicAdd(cnt + i0, 1);
        atomicAdd(cnt + i1, 1);
    }
}

// offs[e] padded to multiples of 128; offs[8],offs[9] = shared-expert bases
__global__ void scan_kernel(const int* __restrict__ cnt, int* __restrict__ offs,
                            int* __restrict__ cnt2) {
    if (threadIdx.x == 0) {
        int o = 0;
        for (int e = 0; e < 8; ++e) { offs[e] = o; o += (cnt[e] + 127) & ~127; }
        offs[8] = o; offs[9] = o + 4096;
    }
    if (threadIdx.x < 8) cnt2[threadIdx.x] = 0;
}

__global__ __launch_bounds__(256) void scatter_kernel(
        const int* __restrict__ te, const float* __restrict__ tw,
        const int* __restrict__ offs, int* __restrict__ cnt2,
        int* __restrict__ ptok, float* __restrict__ pw) {
    int t = blockIdx.x * 256 + threadIdx.x;
    int e0 = te[2 * t], e1 = te[2 * t + 1];
    int s0 = atomicAdd(cnt2 + e0, 1);
    int pos0 = offs[e0] + s0;
    ptok[pos0] = t; pw[pos0] = tw[2 * t];
    int s1 = atomicAdd(cnt2 + e1, 1);
    int pos1 = offs[e1] + s1;
    ptok[pos1] = t; pw[pos1] = tw[2 * t + 1];
    int b8 = offs[8], b9 = offs[9];
    ptok[b8 + t] = t; pw[b8 + t] = 0.5f;
    ptok[b9 + t] = t; pw[b9 + t] = 0.5f;
}

// ------- weight pack: src fp32 [R(k)][C(n)] -> fragment-packed bf16 ----
// layout: [z][ntile(C/128)][kchunk(R/64)][frag8][kstep2][lane64][8]
__global__ __launch_bounds__(256) void wpack_kernel(
        const float* __restrict__ srcA, const float* __restrict__ srcB, int splitZ,
        int R, int C, unsigned short* __restrict__ dst) {
    int z = blockIdx.z;
    const float* src = (z < splitZ) ? srcA + (size_t)z * R * C
                                    : srcB + (size_t)(z - splitZ) * R * C;
    int c0 = blockIdx.x * 64, r0 = blockIdx.y * 64;
    __shared__ float tile[64][65];
    int t = threadIdx.x;
    int rl = t >> 4, cl = (t & 15) * 4;
#pragma unroll
    for (int p = 0; p < 4; ++p) {
        int r = p * 16 + rl;
        const float4 v = *(const float4*)&src[(size_t)(r0 + r) * C + c0 + cl];
        tile[r][cl] = v.x; tile[r][cl + 1] = v.y; tile[r][cl + 2] = v.z; tile[r][cl + 3] = v.w;
    }
    __syncthreads();
    int NT = C >> 7, NKC = R >> 6;
    int ntile = c0 >> 7, kc = blockIdx.y, frag0 = (blockIdx.x & 1) * 4;
    unsigned short* base = dst + ((size_t)(z * NT + ntile) * NKC + kc) * 8192 + frag0 * 1024;
#pragma unroll
    for (int w = 0; w < 2; ++w) {
        int si = w * 256 + t;            // 0..511
        int fl = si >> 7, rem = si & 127;
        int kst = rem >> 6, l2 = rem & 63;
        int n_l = fl * 16 + (l2 & 15);
        int k_l = kst * 32 + (l2 >> 4) * 8;
        unsigned int u[4];
#pragma unroll
        for (int i = 0; i < 4; ++i) {
            unsigned short lo = f2bf(tile[k_l + 2 * i][n_l]);
            unsigned short hi = f2bf(tile[k_l + 2 * i + 1][n_l]);
            u[i] = lo | ((unsigned)hi << 16);
        }
        *(uint4*)(base + (size_t)si * 8) = make_uint4(u[0], u[1], u[2], u[3]);
    }
}

// ------- A pack (phase 1): gather x rows by ptok, cast, fragment-pack --
// dst layout: [gm][kchunk16][frag8][kstep2][lane64][8]
__global__ __launch_bounds__(256) void apack_kernel(
        const float* __restrict__ x, const int* __restrict__ counts,
        const int* __restrict__ offs, const int* __restrict__ ptok,
        unsigned short* __restrict__ dst) {
    int z = blockIdx.z;
    int cnt = (z < NEXP) ? counts[z] : 4096;
    int pbase = offs[z];
    int mtile = blockIdx.y;
    if (mtile * 128 >= cnt) return;
    int kc = blockIdx.x;
    int gm = (pbase >> 7) + mtile;
    unsigned short* d = dst + ((size_t)gm * 16 + kc) * 8192;
    int t = threadIdx.x;
#pragma unroll
    for (int w = 0; w < 4; ++w) {
        int si = w * 256 + t;            // 0..1023
        int fl = si >> 7, rem = si & 127;
        int kst = rem >> 6, l2 = rem & 63;
        int row = fl * 16 + (l2 & 15);
        int k0 = kc * 64 + kst * 32 + (l2 >> 4) * 8;
        int idx = mtile * 128 + row;
        if (idx >= cnt) idx = cnt - 1;
        int tok = ptok[pbase + idx];
        const float4* p = (const float4*)(x + (size_t)tok * D_MODEL + k0);
        float4 a = p[0], b = p[1];
        unsigned int u0 = f2bf(a.x) | ((unsigned)f2bf(a.y) << 16);
        unsigned int u1 = f2bf(a.z) | ((unsigned)f2bf(a.w) << 16);
        unsigned int u2 = f2bf(b.x) | ((unsigned)f2bf(b.y) << 16);
        unsigned int u3 = f2bf(b.z) | ((unsigned)f2bf(b.w) << 16);
        *(uint4*)(d + (size_t)si * 8) = make_uint4(u0, u1, u2, u3);
    }
}

// ---------------- grouped MFMA GEMM, coalesced staging -----------------
// A: [gm][NKC][8192] fragment-packed. B: [z][NT][NKC][8192] fragment-packed.
// Tile BM=BN=128, BK=64; 4 waves 2x2; 16x16x32 bf16 MFMA.
// PHASE 1: epilogue gelu(.+b1) -> writes Aout fragment-packed for phase 2.
// PHASE 2: epilogue (.+b2)*w -> atomicAdd into out rows by token.
template <int NKC, int NT, int PHASE>
__global__ __launch_bounds__(256) void moe_gemm(
        const unsigned short* __restrict__ Wp,
        const unsigned short* __restrict__ Ap,
        const float* __restrict__ bias, const float* __restrict__ sbias,
        const int* __restrict__ counts, const int* __restrict__ offs,
        const int* __restrict__ ptok, const float* __restrict__ pw,
        unsigned short* __restrict__ Aout, float* __restrict__ out) {
    const int z = blockIdx.z;
    const int cnt = (z < NEXP) ? counts[z] : 4096;
    const int pbase = offs[z];
    const int mtile = blockIdx.y;
    if (mtile * 128 >= cnt) return;
    const int ntile = blockIdx.x;
    const int tid = threadIdx.x;
    const int wave = tid >> 6, lane = tid & 63;
    const int wm = wave >> 1, wn = wave & 1;
    const int gm = (pbase >> 7) + mtile;
    const int NDIM = NT * 128;

    __shared__ __align__(16) short smem[4 * 64 * 72];  // 36864 B
    short* As = smem;
    short* Bs = smem + 8192;

    const unsigned short* Ablk = Ap + (size_t)gm * NKC * 8192;
    const unsigned short* Bblk = Wp + (size_t)(z * NT + ntile) * NKC * 8192;
    const float* be = (z < NEXP) ? bias + (size_t)z * NDIM
                                 : sbias + (size_t)(z - NEXP) * NDIM;

    floatx4 acc[4][4];
#pragma unroll
    for (int s = 0; s < 4; ++s)
#pragma unroll
        for (int n = 0; n < 4; ++n) acc[s][n] = (floatx4){0.f, 0.f, 0.f, 0.f};

    for (int kc = 0; kc < NKC; ++kc) {
        __syncthreads();
        const unsigned short* ga = Ablk + (size_t)kc * 8192 + wave * 2048 + lane * 8;
        const unsigned short* gb = Bblk + (size_t)kc * 8192 + wave * 2048 + lane * 8;
        short* la = As + wave * 2048;
        short* lb = Bs + wave * 2048;
#pragma unroll
        for (int q = 0; q < 4; ++q) {
            gll16(ga + q * 512, la + q * 512);
            gll16(gb + q * 512, lb + q * 512);
        }
        __syncthreads();
#pragma unroll
        for (int ks = 0; ks < 2; ++ks) {
            short8 af[4], bfr[4];
#pragma unroll
            for (int s = 0; s < 4; ++s)
                af[s] = *(const short8*)(As + ((wm * 4 + s) * 2 + ks) * 512 + lane * 8);
#pragma unroll
            for (int n = 0; n < 4; ++n)
                bfr[n] = *(const short8*)(Bs + ((wn * 4 + n) * 2 + ks) * 512 + lane * 8);
#pragma unroll
            for (int s = 0; s < 4; ++s)
#pragma unroll
                for (int n = 0; n < 4; ++n)
                    acc[s][n] = __builtin_amdgcn_mfma_f32_16x16x32_bf16(af[s], bfr[n], acc[s][n], 0, 0, 0);
        }
    }

    if (PHASE == 1) {
        // route 64x64 wave tile through LDS; emit fragment-packed rows for phase 2
        __syncthreads();
        short* tile = smem + wave * (64 * 72);
#pragma unroll
        for (int n = 0; n < 4; ++n) {
            float bv = be[ntile * 128 + wn * 64 + n * 16 + (lane & 15)];
#pragma unroll
            for (int s = 0; s < 4; ++s) {
#pragma unroll
                for (int reg = 0; reg < 4; ++reg) {
                    int r_l = s * 16 + (lane >> 4) * 4 + reg;
                    int c_l = n * 16 + (lane & 15);
                    float v = acc[s][n][reg] + bv;
                    float g = 0.5f * v * (1.0f + erff(v * 0.70710678118654752f));
                    tile[r_l * 72 + c_l] = (short)f2bf(g);
                }
            }
        }
        // per-wave tile: LDS write->read within one wave, no barrier needed
        unsigned short* obase = Aout + ((size_t)gm * 64 + (ntile * 2 + wn)) * 8192
                              + (size_t)wm * 4096;
#pragma unroll
        for (int it = 0; it < 8; ++it) {
            int si = it * 64 + lane;     // 0..511
            int fl = si >> 7, rem = si & 127;
            int kst = rem >> 6, l2 = rem & 63;
            int r_l = fl * 16 + (l2 & 15);
            int c_l = kst * 32 + (l2 >> 4) * 8;
            uint4 v = *(const uint4*)(tile + r_l * 72 + c_l);
            *(uint4*)(obase + (size_t)si * 8) = v;
        }
    } else {
        const int gcb = ntile * 128 + wn * 64;
        const int rbq = mtile * 128 + wm * 64 + ((lane >> 4) * 4);
        float bv[4];
        int cc[4];
#pragma unroll
        for (int n = 0; n < 4; ++n) {
            cc[n] = gcb + n * 16 + (lane & 15);
            bv[n] = be[cc[n]];
        }
#pragma unroll
        for (int s = 0; s < 4; ++s) {
#pragma unroll
            for (int reg = 0; reg < 4; ++reg) {
                int r = rbq + s * 16 + reg;
                if (r < cnt) {
                    int p = pbase + r;
                    int tok = ptok[p];
                    float w = pw[p];
                    float* orow = out + (size_t)tok * D_MODEL;
#pragma unroll
                    for (int n = 0; n < 4; ++n)
                        atomicAdd(orow + cc[n], (acc[s][n][reg] + bv[n]) * w);
                }
            }
        }
    }
}

extern "C" void kernel_launch(void* const* d_in, const int* in_sizes, int n_in,
                              void* d_out, int out_size, void* d_ws, size_t ws_size,
                              hipStream_t stream) {
    const float* x   = (const float*)d_in[0];
    const float* rW  = (const float*)d_in[1];
    const float* rb  = (const float*)d_in[2];
    const float* W1  = (const float*)d_in[3];
    const float* b1  = (const float*)d_in[4];
    const float* W2  = (const float*)d_in[5];
    const float* b2  = (const float*)d_in[6];
    const float* sW1 = (const float*)d_in[7];
    const float* sb1 = (const float*)d_in[8];
    const float* sW2 = (const float*)d_in[9];
    const float* sb2 = (const float*)d_in[10];
    float* out = (float*)d_out;

    const int T = in_sizes[0] / D_MODEL;     // 4096
    const int MAXROWS = 18432;               // padded pair capacity (144 gm tiles)

    char* ws = (char*)d_ws;
    size_t o = 0;
    auto alloc = [&](size_t bytes) -> void* {
        void* p = ws + o;
        o += (bytes + 255) & ~(size_t)255;
        return p;
    };
    unsigned short* Wp1  = (unsigned short*)alloc((size_t)NVEXP * 32 * 16 * 8192 * 2);
    unsigned short* Wp2  = (unsigned short*)alloc((size_t)NVEXP * 8 * 64 * 8192 * 2);
    unsigned short* Ap1  = (unsigned short*)alloc((size_t)(MAXROWS / 128) * 16 * 8192 * 2);
    unsigned short* Ap2  = (unsigned short*)alloc((size_t)(MAXROWS / 128) * 64 * 8192 * 2);
    int*   ptok = (int*)alloc((size_t)MAXROWS * 4);
    float* pwb  = (float*)alloc((size_t)MAXROWS * 4);
    int*   te   = (int*)alloc((size_t)T * 2 * 4);
    float* tw   = (float*)alloc((size_t)T * 2 * 4);
    int*   cnt  = (int*)alloc(64);
    int*   offs = (int*)alloc(64);
    int*   cnt2 = (int*)alloc(64);
    (void)ws_size; (void)n_in;

    hipMemsetAsync(out, 0, (size_t)out_size * 4, stream);
    hipMemsetAsync(cnt, 0, 64, stream);

    router_kernel<<<T / 4, 256, 0, stream>>>(x, rW, rb, te, tw, cnt);
    scan_kernel<<<1, 64, 0, stream>>>(cnt, offs, cnt2);
    scatter_kernel<<<T / 256, 256, 0, stream>>>(te, tw, offs, cnt2, ptok, pwb);

    apack_kernel<<<dim3(16, 32, NVEXP), 256, 0, stream>>>(x, cnt, offs, ptok, Ap1);
    // W1 group: [1024(k)][4096(n)] -> packed, NT=32, NKC=16
    wpack_kernel<<<dim3(HIDDEN / 64, D_MODEL / 64, NVEXP), 256, 0, stream>>>(
        W1, sW1, NEXP, D_MODEL, HIDDEN, Wp1);
    // W2 group: [4096(k)][1024(n)] -> packed, NT=8, NKC=64
    wpack_kernel<<<dim3(D_MODEL / 64, HIDDEN / 64, NVEXP), 256, 0, stream>>>(
        W2, sW2, NEXP, HIDDEN, D_MODEL, Wp2);

    moe_gemm<16, 32, 1><<<dim3(32, 32, NVEXP), 256, 0, stream>>>(
        Wp1, Ap1, b1, sb1, cnt, offs, ptok, pwb, Ap2, nullptr);
    moe_gemm<64, 8, 2><<<dim3(8, 32, NVEXP), 256, 0, stream>>>(
        Wp2, Ap2, b2, sb2, cnt, offs, ptok, pwb, nullptr, out);
}

// Round 3
// 968.622 us; speedup vs baseline: 1.3612x; 1.0896x over previous
//
#include <hip/hip_runtime.h>
#include <math.h>

#define D_MODEL 1024
#define HIDDEN  4096
#define NEXP    8
#define NVEXP   10   // 8 routed + 2 shared

typedef __attribute__((ext_vector_type(8))) short short8;
typedef __attribute__((ext_vector_type(4))) float floatx4;

__device__ __forceinline__ unsigned short f2bf(float f) {
    unsigned int u = __float_as_uint(f);
    unsigned int r = (u + 0x7fffu + ((u >> 16) & 1u)) >> 16;
    return (unsigned short)r;
}

__device__ __forceinline__ void gll16(const void* g, void* l) {
    __builtin_amdgcn_global_load_lds(
        (const __attribute__((address_space(1))) unsigned int*)g,
        (__attribute__((address_space(3))) unsigned int*)l, 16, 0, 0);
}

// ---------------- router: wave per token, fp32 gates -------------------
__global__ __launch_bounds__(256) void router_kernel(
        const float* __restrict__ x, const float* __restrict__ rW,
        const float* __restrict__ rb, int* __restrict__ te, float* __restrict__ tw,
        int* __restrict__ cnt) {
    __shared__ float rws[8 * 1024];   // rws[e][d]
    int tid = threadIdx.x;
    for (int i = tid; i < 8192; i += 256) {
        int dd = i >> 3, e = i & 7;
        rws[e * 1024 + dd] = rW[i];
    }
    __syncthreads();
    int tok = blockIdx.x * 4 + (tid >> 6);
    int lane = tid & 63;
    const float* xr = x + (size_t)tok * D_MODEL;
    float acc[8];
#pragma unroll
    for (int e = 0; e < 8; ++e) acc[e] = 0.f;
    for (int k = 0; k < 16; ++k) {
        int dd = k * 64 + lane;
        float xv = xr[dd];
#pragma unroll
        for (int e = 0; e < 8; ++e) acc[e] += xv * rws[e * 1024 + dd];
    }
#pragma unroll
    for (int m = 1; m < 64; m <<= 1) {
#pragma unroll
        for (int e = 0; e < 8; ++e) acc[e] += __shfl_xor(acc[e], m);
    }
    if (lane == 0) {
        float g[8];
#pragma unroll
        for (int e = 0; e < 8; ++e) g[e] = acc[e] + rb[e];
        int i0 = 0; float v0 = g[0];
#pragma unroll
        for (int e = 1; e < 8; ++e) if (g[e] > v0) { v0 = g[e]; i0 = e; }
        int i1 = -1; float v1 = -1e30f;
#pragma unroll
        for (int e = 0; e < 8; ++e) if (e != i0 && g[e] > v1) { v1 = g[e]; i1 = e; }
        float ex = expf(v1 - v0);
        float p0 = 1.0f / (1.0f + ex);
        float p1 = 1.0f - p0;
        te[tok * 2] = i0; te[tok * 2 + 1] = i1;
        tw[tok * 2] = p0; tw[tok * 2 + 1] = p1;
        atomicAdd(cnt + i0, 1);
        atomicAdd(cnt + i1, 1);
    }
}

// offs[e] padded to multiples of 128; offs[8] = shared-A base (also z=8 out base),
// offs[9] = z=9 out base
__global__ void scan_kernel(const int* __restrict__ cnt, int* __restrict__ offs,
                            int* __restrict__ cnt2) {
    if (threadIdx.x == 0) {
        int o = 0;
        for (int e = 0; e < 8; ++e) { offs[e] = o; o += (cnt[e] + 127) & ~127; }
        offs[8] = o; offs[9] = o + 4096;
    }
    if (threadIdx.x < 8) cnt2[threadIdx.x] = 0;
}

__global__ __launch_bounds__(256) void scatter_kernel(
        const int* __restrict__ te, const float* __restrict__ tw,
        const int* __restrict__ offs, int* __restrict__ cnt2,
        int* __restrict__ ptok, float* __restrict__ pw, int* __restrict__ tpair) {
    int t = blockIdx.x * 256 + threadIdx.x;
    int e0 = te[2 * t], e1 = te[2 * t + 1];
    int s0 = atomicAdd(cnt2 + e0, 1);
    int pos0 = offs[e0] + s0;
    ptok[pos0] = t; pw[pos0] = tw[2 * t];
    int s1 = atomicAdd(cnt2 + e1, 1);
    int pos1 = offs[e1] + s1;
    ptok[pos1] = t; pw[pos1] = tw[2 * t + 1];
    int b8 = offs[8], b9 = offs[9];
    ptok[b8 + t] = t; pw[b8 + t] = 0.5f;
    ptok[b9 + t] = t; pw[b9 + t] = 0.5f;
    tpair[4 * t + 0] = pos0; tpair[4 * t + 1] = pos1;
    tpair[4 * t + 2] = b8 + t; tpair[4 * t + 3] = b9 + t;
}

// ------- weight pack: src fp32 [R(k)][C(n)] -> fragment-packed bf16 ----
// layout: [z][ntile(C/256)][kc(R/64)][frag16][kstep2][lane64][8]  (32KB pages)
__global__ __launch_bounds__(256) void wpack_kernel(
        const float* __restrict__ srcA, const float* __restrict__ srcB, int splitZ,
        int R, int C, unsigned short* __restrict__ dst) {
    int z = blockIdx.z;
    const float* src = (z < splitZ) ? srcA + (size_t)z * R * C
                                    : srcB + (size_t)(z - splitZ) * R * C;
    int c0 = blockIdx.x * 64, r0 = blockIdx.y * 64;
    __shared__ float tile[64][65];
    int t = threadIdx.x;
    int rl = t >> 4, cl = (t & 15) * 4;
#pragma unroll
    for (int p = 0; p < 4; ++p) {
        int r = p * 16 + rl;
        const float4 v = *(const float4*)&src[(size_t)(r0 + r) * C + c0 + cl];
        tile[r][cl] = v.x; tile[r][cl + 1] = v.y; tile[r][cl + 2] = v.z; tile[r][cl + 3] = v.w;
    }
    __syncthreads();
    int NT = C >> 8, NKC = R >> 6;
    int ntile = c0 >> 8, f0 = (c0 >> 4) & 15, kc = blockIdx.y;
    unsigned short* base = dst + ((size_t)(z * NT + ntile) * NKC + kc) * 16384;
#pragma unroll
    for (int w = 0; w < 2; ++w) {
        int si = w * 256 + t;            // 0..511
        int fl = si >> 7, rem = si & 127;
        int kst = rem >> 6, l2 = rem & 63;
        int n_l = fl * 16 + (l2 & 15);
        int k_l = kst * 32 + (l2 >> 4) * 8;
        unsigned int u[4];
#pragma unroll
        for (int i = 0; i < 4; ++i) {
            unsigned short lo = f2bf(tile[k_l + 2 * i][n_l]);
            unsigned short hi = f2bf(tile[k_l + 2 * i + 1][n_l]);
            u[i] = lo | ((unsigned)hi << 16);
        }
        *(uint4*)(base + ((size_t)(f0 + fl) * 2 + kst) * 512 + (size_t)l2 * 8) =
            make_uint4(u[0], u[1], u[2], u[3]);
    }
}

// ------- A pack (phase 1): gather x rows by ptok, cast, fragment-pack --
// dst layout: [gm128][kc16][frag8][kstep2][lane64][8]  (16KB pages)
__global__ __launch_bounds__(256) void apack_kernel(
        const float* __restrict__ x, const int* __restrict__ counts,
        const int* __restrict__ offs, const int* __restrict__ ptok,
        unsigned short* __restrict__ dst) {
    int z = blockIdx.z;               // 0..8 (8 = shared section, written once)
    int cnt = (z < NEXP) ? counts[z] : 4096;
    int pbase = offs[z];
    int mtile = blockIdx.y;
    if (mtile * 128 >= cnt) return;
    int kc = blockIdx.x;
    int gm = (pbase >> 7) + mtile;
    unsigned short* d = dst + ((size_t)gm * 16 + kc) * 8192;
    int t = threadIdx.x;
#pragma unroll
    for (int w = 0; w < 4; ++w) {
        int si = w * 256 + t;            // 0..1023
        int fl = si >> 7, rem = si & 127;
        int kst = rem >> 6, l2 = rem & 63;
        int row = fl * 16 + (l2 & 15);
        int k0 = kc * 64 + kst * 32 + (l2 >> 4) * 8;
        int idx = mtile * 128 + row;
        if (idx >= cnt) idx = cnt - 1;
        int tok = ptok[pbase + idx];
        const float4* p = (const float4*)(x + (size_t)tok * D_MODEL + k0);
        float4 a = p[0], b = p[1];
        unsigned int u0 = f2bf(a.x) | ((unsigned)f2bf(a.y) << 16);
        unsigned int u1 = f2bf(a.z) | ((unsigned)f2bf(a.w) << 16);
        unsigned int u2 = f2bf(b.x) | ((unsigned)f2bf(b.y) << 16);
        unsigned int u3 = f2bf(b.z) | ((unsigned)f2bf(b.w) << 16);
        *(uint4*)(d + (size_t)si * 8) = make_uint4(u0, u1, u2, u3);
    }
}

// ---------------- grouped MFMA GEMM: BM=128, BN=256, BK=64 -------------
// 4 waves (2x2), wave tile 64x128, acc[4][8]. A pages 16KB, B pages 32KB.
// PHASE 1: epilogue gelu(.+b1) -> writes Aout fragment-packed (phase-2 A).
// PHASE 2: epilogue (.+b2) -> plain stores into per-pair buf rows.
template <int NKC, int NT, int PHASE>
__global__ __launch_bounds__(256, 2) void moe_gemm(
        const unsigned short* __restrict__ Wp,
        const unsigned short* __restrict__ Ap,
        const float* __restrict__ bias, const float* __restrict__ sbias,
        const int* __restrict__ counts, const int* __restrict__ offs,
        unsigned short* __restrict__ Aout, float* __restrict__ buf) {
    const int z = blockIdx.z;
    const int cnt = (z < NEXP) ? counts[z] : 4096;
    const int mtile = blockIdx.y;
    if (mtile * 128 >= cnt) return;
    const int outbase = offs[z];
    const int inbase = (PHASE == 1 && z >= NEXP) ? offs[8] : outbase;
    const int ntile = blockIdx.x;
    const int tid = threadIdx.x;
    const int wave = tid >> 6, lane = tid & 63;
    const int wm = wave >> 1, wn = wave & 1;
    const int in_gm = (inbase >> 7) + mtile;
    const int NDIM = NT * 256;

    __shared__ __align__(16) short smem[24576];   // 48 KB: As 16KB + Bs 32KB
    short* As = smem;
    short* Bs = smem + 8192;

    const unsigned short* Apg = Ap + (size_t)in_gm * NKC * 8192;
    const unsigned short* Bpg = Wp + (size_t)(z * NT + ntile) * NKC * 16384;
    const float* be = (z < NEXP) ? bias + (size_t)z * NDIM
                                 : sbias + (size_t)(z - NEXP) * NDIM;

    floatx4 acc[4][8];
#pragma unroll
    for (int s = 0; s < 4; ++s)
#pragma unroll
        for (int n = 0; n < 8; ++n) acc[s][n] = (floatx4){0.f, 0.f, 0.f, 0.f};

    for (int kc = 0; kc < NKC; ++kc) {
        __syncthreads();
        const unsigned short* ga = Apg + (size_t)kc * 8192 + tid * 8;
        const unsigned short* gb = Bpg + (size_t)kc * 16384 + tid * 8;
        short* la = As + tid * 8;
        short* lb = Bs + tid * 8;
#pragma unroll
        for (int q = 0; q < 4; ++q) gll16(ga + q * 2048, la + q * 2048);
#pragma unroll
        for (int q = 0; q < 8; ++q) gll16(gb + q * 2048, lb + q * 2048);
        __syncthreads();
#pragma unroll
        for (int ks = 0; ks < 2; ++ks) {
            short8 af[4], bfr[8];
#pragma unroll
            for (int s = 0; s < 4; ++s)
                af[s] = *(const short8*)(As + ((wm * 4 + s) * 2 + ks) * 512 + lane * 8);
#pragma unroll
            for (int n = 0; n < 8; ++n)
                bfr[n] = *(const short8*)(Bs + ((wn * 8 + n) * 2 + ks) * 512 + lane * 8);
#pragma unroll
            for (int s = 0; s < 4; ++s)
#pragma unroll
                for (int n = 0; n < 8; ++n)
                    acc[s][n] = __builtin_amdgcn_mfma_f32_16x16x32_bf16(af[s], bfr[n], acc[s][n], 0, 0, 0);
        }
    }

    float bv[8];
#pragma unroll
    for (int n = 0; n < 8; ++n)
        bv[n] = be[ntile * 256 + wn * 128 + n * 16 + (lane & 15)];

    if (PHASE == 1) {
        __syncthreads();   // all waves done reading staging LDS
        short* tl = smem + wave * 2176;   // 16 rows x 136 pitch (shorts)
        const int out_gm = (outbase >> 7) + mtile;
        const int rq = (lane >> 4) * 4;
#pragma unroll
        for (int s = 0; s < 4; ++s) {
            // write 16x128 chunk (bias + exact gelu), C-layout -> LDS
#pragma unroll
            for (int n = 0; n < 8; ++n) {
#pragma unroll
                for (int reg = 0; reg < 4; ++reg) {
                    float v = acc[s][n][reg] + bv[n];
                    float g = 0.5f * v * (1.0f + erff(v * 0.70710678118654752f));
                    tl[(rq + reg) * 136 + n * 16 + (lane & 15)] = (short)f2bf(g);
                }
            }
            // read fragment-ordered, store 16B coalesced into phase-2 A pages
            const int f = wm * 4 + s;
#pragma unroll
            for (int kh = 0; kh < 2; ++kh) {
#pragma unroll
                for (int kst = 0; kst < 2; ++kst) {
                    uint4 u = *(const uint4*)(tl + (lane & 15) * 136 + kh * 64 + kst * 32 + (lane >> 4) * 8);
                    int kc2 = ntile * 4 + wn * 2 + kh;
                    *(uint4*)(Aout + ((size_t)out_gm * 64 + kc2) * 8192
                              + ((size_t)(f * 2 + kst) * 64 + lane) * 8) = u;
                }
            }
        }
    } else {
        const int prow0 = outbase + mtile * 128 + wm * 64;
#pragma unroll
        for (int s = 0; s < 4; ++s) {
#pragma unroll
            for (int reg = 0; reg < 4; ++reg) {
                int p = prow0 + s * 16 + (lane >> 4) * 4 + reg;
                float* br = buf + (size_t)p * D_MODEL + ntile * 256 + wn * 128;
#pragma unroll
                for (int n = 0; n < 8; ++n)
                    br[n * 16 + (lane & 15)] = acc[s][n][reg] + bv[n];
            }
        }
    }
}

// ---------------- final reduce: out[t] = sum_j pw[pj] * buf[pj] --------
__global__ __launch_bounds__(256) void reduce_kernel(
        const float* __restrict__ buf, const int* __restrict__ tpair,
        const float* __restrict__ pw, float* __restrict__ out) {
    int t = blockIdx.x;
    int c = threadIdx.x * 4;
    int p0 = tpair[4 * t], p1 = tpair[4 * t + 1];
    int p2 = tpair[4 * t + 2], p3 = tpair[4 * t + 3];
    float w0 = pw[p0], w1 = pw[p1], w2 = pw[p2], w3 = pw[p3];
    float4 a = *(const float4*)(buf + (size_t)p0 * D_MODEL + c);
    float4 b = *(const float4*)(buf + (size_t)p1 * D_MODEL + c);
    float4 d = *(const float4*)(buf + (size_t)p2 * D_MODEL + c);
    float4 e = *(const float4*)(buf + (size_t)p3 * D_MODEL + c);
    float4 o;
    o.x = w0 * a.x + w1 * b.x + w2 * d.x + w3 * e.x;
    o.y = w0 * a.y + w1 * b.y + w2 * d.y + w3 * e.y;
    o.z = w0 * a.z + w1 * b.z + w2 * d.z + w3 * e.z;
    o.w = w0 * a.w + w1 * b.w + w2 * d.w + w3 * e.w;
    *(float4*)(out + (size_t)t * D_MODEL + c) = o;
}

extern "C" void kernel_launch(void* const* d_in, const int* in_sizes, int n_in,
                              void* d_out, int out_size, void* d_ws, size_t ws_size,
                              hipStream_t stream) {
    const float* x   = (const float*)d_in[0];
    const float* rW  = (const float*)d_in[1];
    const float* rb  = (const float*)d_in[2];
    const float* W1  = (const float*)d_in[3];
    const float* b1  = (const float*)d_in[4];
    const float* W2  = (const float*)d_in[5];
    const float* b2  = (const float*)d_in[6];
    const float* sW1 = (const float*)d_in[7];
    const float* sb1 = (const float*)d_in[8];
    const float* sW2 = (const float*)d_in[9];
    const float* sb2 = (const float*)d_in[10];
    float* out = (float*)d_out;

    const int T = in_sizes[0] / D_MODEL;     // 4096
    const int MAXROWS = 18432;               // padded pair-row capacity (144 gm128)

    char* ws = (char*)d_ws;
    size_t o = 0;
    auto alloc = [&](size_t bytes) -> void* {
        void* p = ws + o;
        o += (bytes + 255) & ~(size_t)255;
        return p;
    };
    unsigned short* Wp1  = (unsigned short*)alloc((size_t)NVEXP * 16 * 16 * 16384 * 2);
    unsigned short* Wp2  = (unsigned short*)alloc((size_t)NVEXP * 4 * 64 * 16384 * 2);
    unsigned short* Ap1  = (unsigned short*)alloc((size_t)(MAXROWS / 128) * 16 * 8192 * 2);
    unsigned short* Ap2  = (unsigned short*)alloc((size_t)(MAXROWS / 128) * 64 * 8192 * 2);
    int*   ptok  = (int*)alloc((size_t)MAXROWS * 4);
    float* pwb   = (float*)alloc((size_t)MAXROWS * 4);
    int*   te    = (int*)alloc((size_t)T * 2 * 4);
    float* tw    = (float*)alloc((size_t)T * 2 * 4);
    int*   tpair = (int*)alloc((size_t)T * 4 * 4);
    int*   cnt   = (int*)alloc(64);
    int*   offs  = (int*)alloc(64);
    int*   cnt2  = (int*)alloc(64);
    // buf aliases Wp1 (phase 1 finished reading Wp1 before phase 2 writes buf):
    // needs 18432*1024*4 = 75.5 MB <= Wp1's 83.9 MB
    float* buf = (float*)Wp1;
    (void)ws_size; (void)n_in;

    hipMemsetAsync(cnt, 0, 64, stream);

    router_kernel<<<T / 4, 256, 0, stream>>>(x, rW, rb, te, tw, cnt);
    scan_kernel<<<1, 64, 0, stream>>>(cnt, offs, cnt2);
    scatter_kernel<<<T / 256, 256, 0, stream>>>(te, tw, offs, cnt2, ptok, pwb, tpair);

    apack_kernel<<<dim3(16, 32, 9), 256, 0, stream>>>(x, cnt, offs, ptok, Ap1);
    // W1 group: [1024(k)][4096(n)] -> NT=16, NKC=16
    wpack_kernel<<<dim3(HIDDEN / 64, D_MODEL / 64, NVEXP), 256, 0, stream>>>(
        W1, sW1, NEXP, D_MODEL, HIDDEN, Wp1);
    // W2 group: [4096(k)][1024(n)] -> NT=4, NKC=64
    wpack_kernel<<<dim3(D_MODEL / 64, HIDDEN / 64, NVEXP), 256, 0, stream>>>(
        W2, sW2, NEXP, HIDDEN, D_MODEL, Wp2);

    moe_gemm<16, 16, 1><<<dim3(16, 32, NVEXP), 256, 0, stream>>>(
        Wp1, Ap1, b1, sb1, cnt, offs, Ap2, nullptr);
    moe_gemm<64, 4, 2><<<dim3(4, 32, NVEXP), 256, 0, stream>>>(
        Wp2, Ap2, b2, sb2, cnt, offs, nullptr, buf);

    reduce_kernel<<<T, 256, 0, stream>>>(buf, tpair, pwb, out);
}